// Round 1
// baseline (1812.492 us; speedup 1.0000x reference)
//
#include <hip/hip_runtime.h>
#include <hip/hip_bf16.h>

#define L_SEQ 2048
#define HIDN  2048
#define NH    32
#define BATCHN 4

using bf16x8 = __attribute__((ext_vector_type(8))) short;
using f32x4  = __attribute__((ext_vector_type(4))) float;

__device__ __forceinline__ unsigned short f2bf(float f) {
  union { float f; unsigned u; } v; v.f = f;
  unsigned r = v.u + 0x7fffu + ((v.u >> 16) & 1u);
  return (unsigned short)(r >> 16);
}

__device__ __forceinline__ void gl_lds16(const void* g, void* l) {
  __builtin_amdgcn_global_load_lds(
      (const __attribute__((address_space(1))) unsigned int*)g,
      (__attribute__((address_space(3))) unsigned int*)l, 16, 0, 0);
}

// ---------------- f32 -> bf16 convert (grid-stride over n/4 float4s) ----------
__global__ __launch_bounds__(256) void cvt_bf16_k(const float* __restrict__ in,
                                                  unsigned short* __restrict__ out, int n4) {
  for (int i = blockIdx.x * 256 + threadIdx.x; i < n4; i += gridDim.x * 256) {
    float4 v = *(const float4*)&in[(size_t)i * 4];
    ushort4 o;
    o.x = f2bf(v.x); o.y = f2bf(v.y); o.z = f2bf(v.z); o.w = f2bf(v.w);
    *(ushort4*)&out[(size_t)i * 4] = o;
  }
}

// -------- conv weight transform: wreT[o][k*64+i] = conv_w[o][i][k] (bf16) -----
__global__ __launch_bounds__(256) void wret_k(const float* __restrict__ cw,
                                              unsigned short* __restrict__ out) {
  int idx = blockIdx.x * 256 + threadIdx.x;   // 2048*256 total
  int o = idx >> 8, q = idx & 255;
  int k = q >> 6, i = q & 63;
  out[idx] = f2bf(cw[o * 256 + i * 4 + k]);
}

// ---------------- GEMM: OUT[m][n] = sum_k X[m][k]*W[n][k], bf16 MFMA ----------
template <int SILU>
__global__ __launch_bounds__(256) void gemm_xwt_k(const unsigned short* __restrict__ X,
                                                  const unsigned short* __restrict__ W,
                                                  float* __restrict__ OUT,
                                                  int M, int N, int K) {
  __shared__ __align__(16) unsigned short As[128 * 32];
  __shared__ __align__(16) unsigned short Bs[128 * 32];
  const int tid = threadIdx.x, lane = tid & 63, wid = tid >> 6;
  const int wm = wid >> 1, wn = wid & 1;
  const int m0 = blockIdx.x * 128, n0 = blockIdx.y * 128;
  const int fr = lane & 15, kg = lane >> 4;
  const int sr = lane >> 2, sc = (lane & 3) * 8;   // staging: 4 lanes per row
  f32x4 acc[4][4] = {};
  for (int k0 = 0; k0 < K; k0 += 32) {
    const int cA0 = wid * 16, cA1 = (wid + 4) * 16;   // 16-row chunks per wave-call
    gl_lds16(&X[(size_t)(m0 + cA0 + sr) * K + k0 + sc], &As[cA0 * 32]);
    gl_lds16(&X[(size_t)(m0 + cA1 + sr) * K + k0 + sc], &As[cA1 * 32]);
    gl_lds16(&W[(size_t)(n0 + cA0 + sr) * K + k0 + sc], &Bs[cA0 * 32]);
    gl_lds16(&W[(size_t)(n0 + cA1 + sr) * K + k0 + sc], &Bs[cA1 * 32]);
    __syncthreads();
    bf16x8 af[4], bfr[4];
#pragma unroll
    for (int t = 0; t < 4; ++t) {
      af[t]  = *(const bf16x8*)&As[(wm * 64 + t * 16 + fr) * 32 + kg * 8];
      bfr[t] = *(const bf16x8*)&Bs[(wn * 64 + t * 16 + fr) * 32 + kg * 8];
    }
#pragma unroll
    for (int mt = 0; mt < 4; ++mt)
#pragma unroll
      for (int nt = 0; nt < 4; ++nt)
        acc[mt][nt] = __builtin_amdgcn_mfma_f32_16x16x32_bf16(af[mt], bfr[nt], acc[mt][nt], 0, 0, 0);
    __syncthreads();
  }
#pragma unroll
  for (int mt = 0; mt < 4; ++mt)
#pragma unroll
    for (int nt = 0; nt < 4; ++nt) {
      const int col = n0 + wn * 64 + nt * 16 + fr;
#pragma unroll
      for (int r = 0; r < 4; ++r) {
        const int row = m0 + wm * 64 + mt * 16 + kg * 4 + r;
        float v = acc[mt][nt][r];
        if (SILU) v = v / (1.f + __expf(-v));
        OUT[(size_t)row * N + col] = v;
      }
    }
}

// ------- grouped causal conv as MFMA GEMM; epilogue: (Bc+bias)*dt -> dB -------
__global__ __launch_bounds__(256) void conv_k(const unsigned short* __restrict__ xb,
                                              const unsigned short* __restrict__ wreT,
                                              const float* __restrict__ conv_b,
                                              const float* __restrict__ dt,
                                              float* __restrict__ dB) {
  __shared__ __align__(16) unsigned short x_lds[67 * 64];
  const int l0 = blockIdx.x * 64, g = blockIdx.y, b = blockIdx.z;
  const int tid = threadIdx.x, lane = tid & 63, wid = tid >> 6;
  {
    const int r = tid >> 3, ch = (tid & 7) * 8;
#pragma unroll
    for (int pass = 0; pass < 3; ++pass) {
      int rr = r + pass * 32;
      if (rr < 67) {
        int lg = l0 - 3 + rr;
        bf16x8 v = {};
        if (lg >= 0) v = *(const bf16x8*)&xb[(size_t)(b * L_SEQ + lg) * HIDN + g * 64 + ch];
        *(bf16x8*)&x_lds[rr * 64 + ch] = v;
      }
    }
  }
  __syncthreads();
  const int fr = lane & 15, kg = lane >> 4, wm = wid;
  f32x4 acc[4] = {};
#pragma unroll
  for (int ks = 0; ks < 8; ++ks) {
    bf16x8 a = *(const bf16x8*)&x_lds[(wm * 16 + fr + (ks >> 1)) * 64 + (ks & 1) * 32 + kg * 8];
#pragma unroll
    for (int nt = 0; nt < 4; ++nt) {
      bf16x8 bq = *(const bf16x8*)&wreT[(size_t)(g * 64 + nt * 16 + fr) * 256 + ks * 32 + kg * 8];
      acc[nt] = __builtin_amdgcn_mfma_f32_16x16x32_bf16(a, bq, acc[nt], 0, 0, 0);
    }
  }
#pragma unroll
  for (int nt = 0; nt < 4; ++nt) {
    const int o = nt * 16 + fr;
    const float bias = conv_b[g * 64 + o];
#pragma unroll
    for (int r = 0; r < 4; ++r) {
      const int lg = l0 + wm * 16 + kg * 4 + r;
      const float dtv = dt[b * L_SEQ + lg];
      dB[((size_t)(b * NH + g) * L_SEQ + lg) * 64 + o] = (acc[nt][r] + bias) * dtv;
    }
  }
}

// ------------- sequential selective scan: one wave per (b,h) ------------------
__global__ __launch_bounds__(64) void scan_k(const float* __restrict__ dB,
                                             const float* __restrict__ Aw,
                                             const float* __restrict__ dt,
                                             unsigned short* __restrict__ states) {
  const int bid = blockIdx.x;          // b*32 + h
  const int h = bid & 31, b = bid >> 5;
  const int m = threadIdx.x;
  __shared__ __align__(16) float s_lds[64];
  __shared__ float dt_lds[L_SEQ];
  float A[64];
#pragma unroll
  for (int n4 = 0; n4 < 16; ++n4) {
    float4 v = *(const float4*)&Aw[(size_t)(h * 64 + m) * 64 + n4 * 4];
    A[4 * n4 + 0] = v.x; A[4 * n4 + 1] = v.y; A[4 * n4 + 2] = v.z; A[4 * n4 + 3] = v.w;
  }
  for (int i = m; i < L_SEQ; i += 64) dt_lds[i] = dt[b * L_SEQ + i] * 1.44269504f;
  s_lds[m] = 0.f;
  float s = 0.f;
  __syncthreads();
  const float* dBp = dB + (size_t)bid * L_SEQ * 64;
  unsigned short* stp = states + (size_t)bid * L_SEQ * 64;
  float dcur = dBp[m];
  for (int l = 0; l < L_SEQ; ++l) {
    const int ln = (l < L_SEQ - 1) ? l + 1 : l;
    float dnext = dBp[(size_t)ln * 64 + m];       // prefetch next step's dB
    float a0 = 0.f, a1 = 0.f, a2 = 0.f, a3 = 0.f;
    const float4* s4 = (const float4*)s_lds;
#pragma unroll
    for (int n4 = 0; n4 < 16; ++n4) {
      float4 sv = s4[n4];
      a0 += A[4 * n4 + 0] * sv.x; a1 += A[4 * n4 + 1] * sv.y;
      a2 += A[4 * n4 + 2] * sv.z; a3 += A[4 * n4 + 3] * sv.w;
    }
    float dot = (a0 + a1) + (a2 + a3);
    float e = __builtin_amdgcn_exp2f(dot * dt_lds[l]);
    s = e * s + dcur;
    stp[(size_t)l * 64 + m] = f2bf(s);
    s_lds[m] = s;
    __syncthreads();
    dcur = dnext;
  }
}

// ----- C projection + x*D + silu(gate) multiply; writes hs1 (b,l,hid) f32 -----
__global__ __launch_bounds__(256) void proj_k(const unsigned short* __restrict__ st,
                                              const unsigned short* __restrict__ cwb,
                                              const float* __restrict__ xin,
                                              const float* __restrict__ Dp,
                                              const float* __restrict__ gs,
                                              float* __restrict__ hs1) {
  const int l0 = blockIdx.x * 64, h = blockIdx.y, b = blockIdx.z;
  const int tid = threadIdx.x, lane = tid & 63, wid = tid >> 6;
  const int fr = lane & 15, kg = lane >> 4, wm = wid;
  f32x4 acc[4] = {};
#pragma unroll
  for (int ks = 0; ks < 2; ++ks) {
    bf16x8 a = *(const bf16x8*)&st[((size_t)(b * NH + h) * L_SEQ + l0 + wm * 16 + fr) * 64 + ks * 32 + kg * 8];
#pragma unroll
    for (int nt = 0; nt < 4; ++nt) {
      bf16x8 bq = *(const bf16x8*)&cwb[(size_t)(h * 64 + nt * 16 + fr) * 64 + ks * 32 + kg * 8];
      acc[nt] = __builtin_amdgcn_mfma_f32_16x16x32_bf16(a, bq, acc[nt], 0, 0, 0);
    }
  }
  const float Dh = Dp[h];
#pragma unroll
  for (int nt = 0; nt < 4; ++nt) {
    const int c = h * 64 + nt * 16 + fr;
#pragma unroll
    for (int r = 0; r < 4; ++r) {
      const int lg = l0 + wm * 16 + kg * 4 + r;
      const size_t idx = (size_t)(b * L_SEQ + lg) * HIDN + c;
      float v = acc[nt][r] + xin[idx] * Dh;
      hs1[idx] = v * gs[idx];
    }
  }
}

// --------------------- gated RMSNorm -> bf16 rows -----------------------------
__global__ __launch_bounds__(256) void norm_k(const float* __restrict__ hs1,
                                              const float* __restrict__ nw,
                                              unsigned short* __restrict__ out) {
  const int row = blockIdx.x;
  const float* p = hs1 + (size_t)row * HIDN;
  const int c0 = threadIdx.x * 8;
  float4 u0 = *(const float4*)&p[c0];
  float4 u1 = *(const float4*)&p[c0 + 4];
  float ss = u0.x * u0.x + u0.y * u0.y + u0.z * u0.z + u0.w * u0.w +
             u1.x * u1.x + u1.y * u1.y + u1.z * u1.z + u1.w * u1.w;
#pragma unroll
  for (int off = 32; off; off >>= 1) ss += __shfl_xor(ss, off);
  __shared__ float pr[4];
  if ((threadIdx.x & 63) == 0) pr[threadIdx.x >> 6] = ss;
  __syncthreads();
  float tot = pr[0] + pr[1] + pr[2] + pr[3];
  float rs = rsqrtf(tot * (1.f / HIDN) + 1e-6f);
  bf16x8 res;
  res[0] = (short)f2bf(nw[c0 + 0] * u0.x * rs);
  res[1] = (short)f2bf(nw[c0 + 1] * u0.y * rs);
  res[2] = (short)f2bf(nw[c0 + 2] * u0.z * rs);
  res[3] = (short)f2bf(nw[c0 + 3] * u0.w * rs);
  res[4] = (short)f2bf(nw[c0 + 4] * u1.x * rs);
  res[5] = (short)f2bf(nw[c0 + 5] * u1.y * rs);
  res[6] = (short)f2bf(nw[c0 + 6] * u1.z * rs);
  res[7] = (short)f2bf(nw[c0 + 7] * u1.w * rs);
  *(bf16x8*)&out[(size_t)row * HIDN + c0] = res;
}

extern "C" void kernel_launch(void* const* d_in, const int* in_sizes, int n_in,
                              void* d_out, int out_size, void* d_ws, size_t ws_size,
                              hipStream_t stream) {
  const float* x  = (const float*)d_in[0];
  const float* dt = (const float*)d_in[1];
  const float* gw = (const float*)d_in[2];
  const float* Aw = (const float*)d_in[3];
  const float* cw = (const float*)d_in[4];
  const float* cb = (const float*)d_in[5];
  const float* Cw = (const float*)d_in[6];
  const float* Dp = (const float*)d_in[7];
  const float* nw = (const float*)d_in[8];
  const float* ow = (const float*)d_in[9];
  float* out = (float*)d_out;

  // workspace layout (bytes); x_bf16 region is reused for states after conv.
  char* w = (char*)d_ws;
  unsigned short* xb   = (unsigned short*)(w);                // 32MB
  unsigned short* stb  = (unsigned short*)(w);                // overlay (after conv)
  unsigned short* gwb  = (unsigned short*)(w + 33554432);     // 8MB
  unsigned short* owb  = (unsigned short*)(w + 41943040);     // 8MB
  unsigned short* wret = (unsigned short*)(w + 50331648);     // 1MB
  unsigned short* cwb  = (unsigned short*)(w + 51380224);     // 256KB
  float*          dBf  = (float*)(w + 52428800);              // 64MB
  float*          hs1  = dBf;                                 // overlay (after scan)
  unsigned short* hsb  = (unsigned short*)(w + 119537664);    // 32MB
  if (ws_size < 153092096) return;

  cvt_bf16_k<<<2048, 256, 0, stream>>>(x, xb, 16777216 / 4);
  cvt_bf16_k<<<1024, 256, 0, stream>>>(gw, gwb, 4194304 / 4);
  cvt_bf16_k<<<1024, 256, 0, stream>>>(ow, owb, 4194304 / 4);
  cvt_bf16_k<<<128, 256, 0, stream>>>(Cw, cwb, 131072 / 4);
  wret_k<<<2048, 256, 0, stream>>>(cw, wret);

  dim3 gg(8192 / 128, 2048 / 128);
  gemm_xwt_k<1><<<gg, 256, 0, stream>>>(xb, gwb, out, 8192, 2048, 2048);  // silu(gate) -> d_out
  conv_k<<<dim3(32, 32, 4), 256, 0, stream>>>(xb, wret, cb, dt, dBf);
  scan_k<<<128, 64, 0, stream>>>(dBf, Aw, dt, stb);
  proj_k<<<dim3(32, 32, 4), 256, 0, stream>>>(stb, cwb, x, Dp, out, hs1);
  norm_k<<<8192, 256, 0, stream>>>(hs1, nw, hsb);
  gemm_xwt_k<0><<<gg, 256, 0, stream>>>(hsb, owb, out, 8192, 2048, 2048);
}

// Round 2
// 830.733 us; speedup vs baseline: 2.1818x; 2.1818x over previous
//
#include <hip/hip_runtime.h>
#include <hip/hip_bf16.h>

#define L_SEQ 2048
#define HIDN  2048
#define NH    32
#define BATCHN 4

using bf16x8 = __attribute__((ext_vector_type(8))) short;
using f32x4  = __attribute__((ext_vector_type(4))) float;

__device__ __forceinline__ unsigned short f2bf(float f) {
  union { float f; unsigned u; } v; v.f = f;
  unsigned r = v.u + 0x7fffu + ((v.u >> 16) & 1u);
  return (unsigned short)(r >> 16);
}

__device__ __forceinline__ void gl_lds16(const void* g, void* l) {
  __builtin_amdgcn_global_load_lds(
      (const __attribute__((address_space(1))) unsigned int*)g,
      (__attribute__((address_space(3))) unsigned int*)l, 16, 0, 0);
}

__device__ __forceinline__ float dpp_qperm_add(float x, int ctrl_is_xor1) {
  // compile-time dispatched below; helper kept simple
  return x;
}

template <int CTRL>
__device__ __forceinline__ float qperm(float x) {
  int xi = __builtin_bit_cast(int, x);
  int yi = __builtin_amdgcn_update_dpp(0, xi, CTRL, 0xF, 0xF, true);
  return __builtin_bit_cast(float, yi);
}

// ---------------- f32 -> bf16 convert (grid-stride over n/4 float4s) ----------
__global__ __launch_bounds__(256) void cvt_bf16_k(const float* __restrict__ in,
                                                  unsigned short* __restrict__ out, int n4) {
  for (int i = blockIdx.x * 256 + threadIdx.x; i < n4; i += gridDim.x * 256) {
    float4 v = *(const float4*)&in[(size_t)i * 4];
    ushort4 o;
    o.x = f2bf(v.x); o.y = f2bf(v.y); o.z = f2bf(v.z); o.w = f2bf(v.w);
    *(ushort4*)&out[(size_t)i * 4] = o;
  }
}

// -------- conv weight transform: wreT[o][k*64+i] = conv_w[o][i][k] (bf16) -----
__global__ __launch_bounds__(256) void wret_k(const float* __restrict__ cw,
                                              unsigned short* __restrict__ out) {
  int idx = blockIdx.x * 256 + threadIdx.x;   // 2048*256 total
  int o = idx >> 8, q = idx & 255;
  int k = q >> 6, i = q & 63;
  out[idx] = f2bf(cw[o * 256 + i * 4 + k]);
}

// ---------------- GEMM: OUT[m][n] = sum_k X[m][k]*W[n][k], bf16 MFMA ----------
template <int SILU>
__global__ __launch_bounds__(256) void gemm_xwt_k(const unsigned short* __restrict__ X,
                                                  const unsigned short* __restrict__ W,
                                                  float* __restrict__ OUT,
                                                  int M, int N, int K) {
  __shared__ __align__(16) unsigned short As[128 * 32];
  __shared__ __align__(16) unsigned short Bs[128 * 32];
  const int tid = threadIdx.x, lane = tid & 63, wid = tid >> 6;
  const int wm = wid >> 1, wn = wid & 1;
  const int m0 = blockIdx.x * 128, n0 = blockIdx.y * 128;
  const int fr = lane & 15, kg = lane >> 4;
  const int sr = lane >> 2, sc = (lane & 3) * 8;   // staging: 4 lanes per row
  f32x4 acc[4][4] = {};
  for (int k0 = 0; k0 < K; k0 += 32) {
    const int cA0 = wid * 16, cA1 = (wid + 4) * 16;   // 16-row chunks per wave-call
    gl_lds16(&X[(size_t)(m0 + cA0 + sr) * K + k0 + sc], &As[cA0 * 32]);
    gl_lds16(&X[(size_t)(m0 + cA1 + sr) * K + k0 + sc], &As[cA1 * 32]);
    gl_lds16(&W[(size_t)(n0 + cA0 + sr) * K + k0 + sc], &Bs[cA0 * 32]);
    gl_lds16(&W[(size_t)(n0 + cA1 + sr) * K + k0 + sc], &Bs[cA1 * 32]);
    __syncthreads();
    bf16x8 af[4], bfr[4];
#pragma unroll
    for (int t = 0; t < 4; ++t) {
      af[t]  = *(const bf16x8*)&As[(wm * 64 + t * 16 + fr) * 32 + kg * 8];
      bfr[t] = *(const bf16x8*)&Bs[(wn * 64 + t * 16 + fr) * 32 + kg * 8];
    }
#pragma unroll
    for (int mt = 0; mt < 4; ++mt)
#pragma unroll
      for (int nt = 0; nt < 4; ++nt)
        acc[mt][nt] = __builtin_amdgcn_mfma_f32_16x16x32_bf16(af[mt], bfr[nt], acc[mt][nt], 0, 0, 0);
    __syncthreads();
  }
#pragma unroll
  for (int mt = 0; mt < 4; ++mt)
#pragma unroll
    for (int nt = 0; nt < 4; ++nt) {
      const int col = n0 + wn * 64 + nt * 16 + fr;
#pragma unroll
      for (int r = 0; r < 4; ++r) {
        const int row = m0 + wm * 64 + mt * 16 + kg * 4 + r;
        float v = acc[mt][nt][r];
        if (SILU) v = v / (1.f + __expf(-v));
        OUT[(size_t)row * N + col] = v;
      }
    }
}

// ------- grouped causal conv as MFMA GEMM; epilogue: (Bc+bias)*dt -> dB -------
__global__ __launch_bounds__(256) void conv_k(const unsigned short* __restrict__ xb,
                                              const unsigned short* __restrict__ wreT,
                                              const float* __restrict__ conv_b,
                                              const float* __restrict__ dt,
                                              float* __restrict__ dB) {
  __shared__ __align__(16) unsigned short x_lds[67 * 64];
  const int l0 = blockIdx.x * 64, g = blockIdx.y, b = blockIdx.z;
  const int tid = threadIdx.x, lane = tid & 63, wid = tid >> 6;
  {
    const int r = tid >> 3, ch = (tid & 7) * 8;
#pragma unroll
    for (int pass = 0; pass < 3; ++pass) {
      int rr = r + pass * 32;
      if (rr < 67) {
        int lg = l0 - 3 + rr;
        bf16x8 v = {};
        if (lg >= 0) v = *(const bf16x8*)&xb[(size_t)(b * L_SEQ + lg) * HIDN + g * 64 + ch];
        *(bf16x8*)&x_lds[rr * 64 + ch] = v;
      }
    }
  }
  __syncthreads();
  const int fr = lane & 15, kg = lane >> 4, wm = wid;
  f32x4 acc[4] = {};
#pragma unroll
  for (int ks = 0; ks < 8; ++ks) {
    bf16x8 a = *(const bf16x8*)&x_lds[(wm * 16 + fr + (ks >> 1)) * 64 + (ks & 1) * 32 + kg * 8];
#pragma unroll
    for (int nt = 0; nt < 4; ++nt) {
      bf16x8 bq = *(const bf16x8*)&wreT[(size_t)(g * 64 + nt * 16 + fr) * 256 + ks * 32 + kg * 8];
      acc[nt] = __builtin_amdgcn_mfma_f32_16x16x32_bf16(a, bq, acc[nt], 0, 0, 0);
    }
  }
#pragma unroll
  for (int nt = 0; nt < 4; ++nt) {
    const int o = nt * 16 + fr;
    const float bias = conv_b[g * 64 + o];
#pragma unroll
    for (int r = 0; r < 4; ++r) {
      const int lg = l0 + wm * 16 + kg * 4 + r;
      const float dtv = dt[b * L_SEQ + lg];
      dB[((size_t)(b * NH + g) * L_SEQ + lg) * 64 + o] = (acc[nt][r] + bias) * dtv;
    }
  }
}

// ------------- sequential selective scan v2: 4 waves per (b,h) ----------------
// thread (m = tid>>2, c = tid&3): 16-wide partial of row-m dot, DPP quad reduce.
// s double-buffered in LDS (one barrier/step); dB prefetched 8 steps ahead via
// quad-cooperative loads (lane c holds step l+c of its quad's row m).
__global__ __launch_bounds__(256) void scan_k(const float* __restrict__ dB,
                                              const float* __restrict__ Aw,
                                              const float* __restrict__ dt,
                                              unsigned short* __restrict__ states) {
  const int bid = blockIdx.x;          // b*32 + h
  const int h = bid & 31, b = bid >> 5;
  const int tid = threadIdx.x;
  const int m = tid >> 2, c = tid & 3;
  __shared__ __align__(16) float s_lds[2][64];
  __shared__ __align__(16) float dt_lds[L_SEQ];
  float A16[16];
  {
    const float* Ap = &Aw[(size_t)(h * 64 + m) * 64 + c * 16];
#pragma unroll
    for (int j4 = 0; j4 < 4; ++j4) {
      float4 v = *(const float4*)&Ap[j4 * 4];
      A16[j4 * 4 + 0] = v.x; A16[j4 * 4 + 1] = v.y;
      A16[j4 * 4 + 2] = v.z; A16[j4 * 4 + 3] = v.w;
    }
  }
  for (int i = tid; i < L_SEQ; i += 256) dt_lds[i] = dt[b * L_SEQ + i] * 1.44269504f;
  if (tid < 64) { s_lds[0][tid] = 0.f; s_lds[1][tid] = 0.f; }
  const float* dBp = dB + (size_t)bid * L_SEQ * 64;
  unsigned short* stp = states + (size_t)bid * L_SEQ * 64;
  // prefetch ring: each reg covers 4 steps (lane c -> step l+c of row m)
  float dpf0 = dBp[(size_t)(0 + c) * 64 + m];
  float dpf1 = dBp[(size_t)(4 + c) * 64 + m];
  float s = 0.f;
  int cur = 0;
  __syncthreads();
  for (int g = 0; g < L_SEQ / 4; ++g) {
    const int l0 = g * 4;
    float4 dt4 = *(const float4*)&dt_lds[l0];
    float dnew;
    {
      int idx = l0 + 8 + c;
      if (idx > L_SEQ - 1) idx = L_SEQ - 1;
      dnew = dBp[(size_t)idx * 64 + m];
    }
    const float dcur = dpf0;   // steps l0..l0+3 (lane c holds l0+c)
#pragma unroll
    for (int u = 0; u < 4; ++u) {
      const float4* sp = (const float4*)&s_lds[cur][c * 16];
      float4 s0 = sp[0], s1 = sp[1], s2 = sp[2], s3 = sp[3];
      float p0 = A16[0] * s0.x + A16[1] * s0.y + A16[2] * s0.z + A16[3] * s0.w;
      float p1 = A16[4] * s1.x + A16[5] * s1.y + A16[6] * s1.z + A16[7] * s1.w;
      float p2 = A16[8] * s2.x + A16[9] * s2.y + A16[10] * s2.z + A16[11] * s2.w;
      float p3 = A16[12] * s3.x + A16[13] * s3.y + A16[14] * s3.z + A16[15] * s3.w;
      float p = (p0 + p1) + (p2 + p3);
      p += qperm<0xB1>(p);     // + lane^1
      p += qperm<0x4E>(p);     // + lane^2  -> full quad dot at all 4 lanes
      const float dtl = (u == 0) ? dt4.x : (u == 1) ? dt4.y : (u == 2) ? dt4.z : dt4.w;
      const float e = __builtin_amdgcn_exp2f(p * dtl);
      float dBv;
      if      (u == 0) dBv = qperm<0x00>(dcur);
      else if (u == 1) dBv = qperm<0x55>(dcur);
      else if (u == 2) dBv = qperm<0xAA>(dcur);
      else             dBv = qperm<0xFF>(dcur);
      s = e * s + dBv;
      const int nxt = cur ^ 1;
      if (c == 0) s_lds[nxt][m] = s;
      if (c == 1) stp[(size_t)(l0 + u) * 64 + m] = f2bf(s);
      __syncthreads();
      cur = nxt;
    }
    dpf0 = dpf1; dpf1 = dnew;
  }
}

// ----- C projection + x*D + silu(gate) multiply; writes hs1 (b,l,hid) f32 -----
__global__ __launch_bounds__(256) void proj_k(const unsigned short* __restrict__ st,
                                              const unsigned short* __restrict__ cwb,
                                              const float* __restrict__ xin,
                                              const float* __restrict__ Dp,
                                              const float* __restrict__ gs,
                                              float* __restrict__ hs1) {
  const int l0 = blockIdx.x * 64, h = blockIdx.y, b = blockIdx.z;
  const int tid = threadIdx.x, lane = tid & 63, wid = tid >> 6;
  const int fr = lane & 15, kg = lane >> 4, wm = wid;
  f32x4 acc[4] = {};
#pragma unroll
  for (int ks = 0; ks < 2; ++ks) {
    bf16x8 a = *(const bf16x8*)&st[((size_t)(b * NH + h) * L_SEQ + l0 + wm * 16 + fr) * 64 + ks * 32 + kg * 8];
#pragma unroll
    for (int nt = 0; nt < 4; ++nt) {
      bf16x8 bq = *(const bf16x8*)&cwb[(size_t)(h * 64 + nt * 16 + fr) * 64 + ks * 32 + kg * 8];
      acc[nt] = __builtin_amdgcn_mfma_f32_16x16x32_bf16(a, bq, acc[nt], 0, 0, 0);
    }
  }
  const float Dh = Dp[h];
#pragma unroll
  for (int nt = 0; nt < 4; ++nt) {
    const int c = h * 64 + nt * 16 + fr;
#pragma unroll
    for (int r = 0; r < 4; ++r) {
      const int lg = l0 + wm * 16 + kg * 4 + r;
      const size_t idx = (size_t)(b * L_SEQ + lg) * HIDN + c;
      float v = acc[nt][r] + xin[idx] * Dh;
      hs1[idx] = v * gs[idx];
    }
  }
}

// --------------------- gated RMSNorm -> bf16 rows -----------------------------
__global__ __launch_bounds__(256) void norm_k(const float* __restrict__ hs1,
                                              const float* __restrict__ nw,
                                              unsigned short* __restrict__ out) {
  const int row = blockIdx.x;
  const float* p = hs1 + (size_t)row * HIDN;
  const int c0 = threadIdx.x * 8;
  float4 u0 = *(const float4*)&p[c0];
  float4 u1 = *(const float4*)&p[c0 + 4];
  float ss = u0.x * u0.x + u0.y * u0.y + u0.z * u0.z + u0.w * u0.w +
             u1.x * u1.x + u1.y * u1.y + u1.z * u1.z + u1.w * u1.w;
#pragma unroll
  for (int off = 32; off; off >>= 1) ss += __shfl_xor(ss, off);
  __shared__ float pr[4];
  if ((threadIdx.x & 63) == 0) pr[threadIdx.x >> 6] = ss;
  __syncthreads();
  float tot = pr[0] + pr[1] + pr[2] + pr[3];
  float rs = rsqrtf(tot * (1.f / HIDN) + 1e-6f);
  bf16x8 res;
  res[0] = (short)f2bf(nw[c0 + 0] * u0.x * rs);
  res[1] = (short)f2bf(nw[c0 + 1] * u0.y * rs);
  res[2] = (short)f2bf(nw[c0 + 2] * u0.z * rs);
  res[3] = (short)f2bf(nw[c0 + 3] * u0.w * rs);
  res[4] = (short)f2bf(nw[c0 + 4] * u1.x * rs);
  res[5] = (short)f2bf(nw[c0 + 5] * u1.y * rs);
  res[6] = (short)f2bf(nw[c0 + 6] * u1.z * rs);
  res[7] = (short)f2bf(nw[c0 + 7] * u1.w * rs);
  *(bf16x8*)&out[(size_t)row * HIDN + c0] = res;
}

extern "C" void kernel_launch(void* const* d_in, const int* in_sizes, int n_in,
                              void* d_out, int out_size, void* d_ws, size_t ws_size,
                              hipStream_t stream) {
  const float* x  = (const float*)d_in[0];
  const float* dt = (const float*)d_in[1];
  const float* gw = (const float*)d_in[2];
  const float* Aw = (const float*)d_in[3];
  const float* cw = (const float*)d_in[4];
  const float* cb = (const float*)d_in[5];
  const float* Cw = (const float*)d_in[6];
  const float* Dp = (const float*)d_in[7];
  const float* nw = (const float*)d_in[8];
  const float* ow = (const float*)d_in[9];
  float* out = (float*)d_out;

  // workspace layout (bytes); x_bf16 region is reused for states after conv.
  char* w = (char*)d_ws;
  unsigned short* xb   = (unsigned short*)(w);                // 32MB
  unsigned short* stb  = (unsigned short*)(w);                // overlay (after conv)
  unsigned short* gwb  = (unsigned short*)(w + 33554432);     // 8MB
  unsigned short* owb  = (unsigned short*)(w + 41943040);     // 8MB
  unsigned short* wret = (unsigned short*)(w + 50331648);     // 1MB
  unsigned short* cwb  = (unsigned short*)(w + 51380224);     // 256KB
  float*          dBf  = (float*)(w + 52428800);              // 64MB
  float*          hs1  = dBf;                                 // overlay (after scan)
  unsigned short* hsb  = (unsigned short*)(w + 119537664);    // 32MB
  if (ws_size < 153092096) return;

  cvt_bf16_k<<<2048, 256, 0, stream>>>(x, xb, 16777216 / 4);
  cvt_bf16_k<<<1024, 256, 0, stream>>>(gw, gwb, 4194304 / 4);
  cvt_bf16_k<<<1024, 256, 0, stream>>>(ow, owb, 4194304 / 4);
  cvt_bf16_k<<<128, 256, 0, stream>>>(Cw, cwb, 131072 / 4);
  wret_k<<<2048, 256, 0, stream>>>(cw, wret);

  dim3 gg(8192 / 128, 2048 / 128);
  gemm_xwt_k<1><<<gg, 256, 0, stream>>>(xb, gwb, out, 8192, 2048, 2048);  // silu(gate) -> d_out
  conv_k<<<dim3(32, 32, 4), 256, 0, stream>>>(xb, wret, cb, dt, dBf);
  scan_k<<<128, 256, 0, stream>>>(dBf, Aw, dt, stb);
  proj_k<<<dim3(32, 32, 4), 256, 0, stream>>>(stb, cwb, x, Dp, out, hs1);
  norm_k<<<8192, 256, 0, stream>>>(hs1, nw, hsb);
  gemm_xwt_k<0><<<gg, 256, 0, stream>>>(hsb, owb, out, 8192, 2048, 2048);
}